// Round 10
// baseline (216.672 us; speedup 1.0000x reference)
//
#include <hip/hip_runtime.h>
#include <cstdint>
#include <cstddef>

#define NBINS 65536         // 16-bit histogram of orderable score
#define CAP_C 2048          // candidate pool (pow2, = sort size)
#define NW (CAP_C / 64)     // 64-bit mask words per row = 32
#define WP (NW + 1)         // padded LDS row stride (kills D-column bank conflict)
#define TARGET 1792u        // threshold target (headroom to CAP_C)
#define KMAX 1008           // kept-list capacity
#define MROWS 16            // rows per mask block
#define HB 1024             // hist block threads
#define HE 32768            // keys per hist block (16-bit pack: counts <= HE < 65536)
#define CNT_STRIDE 64       // cnt[b*64]: 256B per counter, no shared lines
#define CPB 64              // compact blocks per batch

typedef unsigned long long u64;

__device__ __forceinline__ unsigned orderable(float f) {
  unsigned b = __float_as_uint(f);
  return (b & 0x80000000u) ? ~b : (b | 0x80000000u);
}

// Pure streaming: also zero-fills hist (no separate init dispatch).
__global__ void decode_kernel(const float4* __restrict__ anchors,
                              const float4* __restrict__ deltas,
                              const float* __restrict__ obj,
                              const int* __restrict__ im_h_p,
                              const int* __restrict__ im_w_p,
                              float4* __restrict__ boxes,
                              unsigned* __restrict__ keys,
                              unsigned* __restrict__ hist,
                              int N, int B) {
#pragma clang fp contract(off)
  int n = blockIdx.x * blockDim.x + threadIdx.x;
  int stride = gridDim.x * blockDim.x;
  for (int j = n; j < B * NBINS; j += stride) hist[j] = 0u;
  if (n >= N) return;
  float imw = (float)(*im_w_p);
  float imh = (float)(*im_h_p);
  float4 a = anchors[n];
  float aw = a.z - a.x;
  float ah = a.w - a.y;
  float acx = a.x + 0.5f * aw;
  float acy = a.y + 0.5f * ah;
  const float LOGM = 4.135166556742356f;  // log(1000/16) rounded to f32
  for (int b = 0; b < B; ++b) {
    size_t off = (size_t)b * N + n;
    float4 d = deltas[off];
    float dw = fminf(d.z, LOGM), dh = fminf(d.w, LOGM);
    float pcx = d.x * aw + acx;
    float pcy = d.y * ah + acy;
    float pw = expf(dw) * aw;
    float ph = expf(dh) * ah;
    float x1 = fminf(fmaxf(pcx - 0.5f * pw, 0.0f), imw);
    float y1 = fminf(fmaxf(pcy - 0.5f * ph, 0.0f), imh);
    float x2 = fminf(fmaxf(pcx + 0.5f * pw, 0.0f), imw);
    float y2 = fminf(fmaxf(pcy + 0.5f * ph, 0.0f), imh);
    boxes[off] = make_float4(x1, y1, x2, y2);
    float area = (x2 - x1) * (y2 - y1);
    float sc = (area > 1.0f) ? obj[off] : -__builtin_inff();
    keys[off] = orderable(sc);
  }
}

// LDS-privatized histogram (round-4 win: killed 140us of contended atomics).
__global__ void __launch_bounds__(HB) hist_kernel(const unsigned* __restrict__ keys,
                                                  unsigned* __restrict__ hist,
                                                  int N) {
  __shared__ unsigned hl[NBINS / 4];  // 16384 uints = 64 KB
  int t = threadIdx.x;
  int half = blockIdx.y, b = blockIdx.z;
  unsigned lo_bin = (unsigned)half * 32768u;
  for (int i = t; i < NBINS / 4; i += HB) hl[i] = 0u;
  __syncthreads();
  const unsigned* kb = keys + (size_t)b * N;
  int base = blockIdx.x * HE;
  int end = base + HE;
  if (end > N) end = N;
  for (int i = base + t; i < end; i += HB) {
    unsigned bin = kb[i] >> 16;
    unsigned lb = bin - lo_bin;
    if (lb < 32768u)
      atomicAdd(&hl[lb >> 1], (lb & 1u) ? 65536u : 1u);
  }
  __syncthreads();
  unsigned* hg = hist + (size_t)b * NBINS + lo_bin;
  for (int i = t; i < NBINS / 4; i += HB) {
    unsigned v = hl[i];
    unsigned clo = v & 0xFFFFu, chi = v >> 16;
    if (clo) atomicAdd(&hg[2 * i], clo);
    if (chi) atomicAdd(&hg[2 * i + 1], chi);
  }
}

// One block per batch: pick bin threshold so [T_lo, NBINS) holds ~TARGET
// candidates (<= CAP_C). Also zeroes cnt[b*CNT_STRIDE] for compact.
__global__ void __launch_bounds__(256) threshold_kernel(const unsigned* __restrict__ hist,
                                                        unsigned* __restrict__ T_lo,
                                                        unsigned* __restrict__ cnt) {
  const int BPT = NBINS / 256;  // 256 bins/thread, contiguous ownership
  __shared__ unsigned s_part[256];
  __shared__ unsigned s_T;
  int b = blockIdx.x, t = threadIdx.x;
  const unsigned* h = hist + (size_t)b * NBINS;
  if (t == 0) { s_T = 0xFFFFFFFFu; cnt[b * CNT_STRIDE] = 0u; }
  unsigned mysum = 0;
  const uint4* h4 = (const uint4*)(h + t * BPT);
  for (int k = 0; k < BPT / 4; ++k) {
    int bin0 = t * BPT + k * 4;
    if (bin0 >= 128) {  // bin>=128 <=> finite score; 128 % 4 == 0
      uint4 v = h4[k];
      mysum += v.x + v.y + v.z + v.w;
    }
  }
  s_part[t] = mysum;
  __syncthreads();
  for (int d = 1; d < 256; d <<= 1) {  // inclusive suffix sum
    unsigned v = (t + d < 256) ? s_part[t + d] : 0u;
    __syncthreads();
    s_part[t] += v;
    __syncthreads();
  }
  unsigned total = s_part[0];
  unsigned target = (TARGET < total) ? TARGET : total;
  unsigned above = (t + 1 < 256) ? s_part[t + 1] : 0u;
  if (total > 0u && above < target && s_part[t] >= target) {  // unique crossing thread
    unsigned c = above;
    for (int k = BPT - 1; k >= 0; --k) {
      unsigned bin = (unsigned)(t * BPT + k);
      if (bin < 128u) break;
      unsigned hv = h[bin];
      c += hv;
      if (c >= target) {
        unsigned T = bin;
        if (c > CAP_C && (c - hv) > 0u) T = bin + 1u;  // never overflow CAP_C
        s_T = T;
        break;
      }
    }
  }
  __syncthreads();
  if (t == 0) T_lo[b] = (total == 0u) ? 0xFFFFFFFFu : s_T;
}

// compact v2: block-aggregated reservation (round-7 win: one atomic/block,
// cnt on private 256B line -> killed 70us of L2 line-ownership ping-pong).
__global__ void __launch_bounds__(1024) compact_kernel(const unsigned* __restrict__ keys,
                                                       const unsigned* __restrict__ T_lo,
                                                       u64* __restrict__ cand,
                                                       unsigned* __restrict__ cnt, int N) {
  __shared__ u64 s_w[4096];  // 32 KB winner staging (total/batch <= ~2048)
  __shared__ unsigned s_n, s_base;
  int b = blockIdx.y, t = threadIdx.x;
  if (t == 0) s_n = 0u;
  __syncthreads();
  unsigned T = T_lo[b];
  int slice = (N + CPB - 1) / CPB;
  int base = blockIdx.x * slice;
  int end = base + slice;
  if (end > N) end = N;
  const unsigned* kb = keys + (size_t)b * N;
  for (int i = base + t; i < end; i += 1024) {
    unsigned u = kb[i];
    if ((u >> 16) >= T) {
      unsigned p = atomicAdd(&s_n, 1u);
      if (p < 4096u)  // ~i: argmax lowest-index tie-break after descending sort
        s_w[p] = ((u64)u << 32) | (unsigned)(~i);
    }
  }
  __syncthreads();
  unsigned n = s_n < 4096u ? s_n : 4096u;
  if (t == 0) s_base = (n > 0u) ? atomicAdd(&cnt[b * CNT_STRIDE], n) : 0u;
  __syncthreads();
  unsigned gb = s_base;
  for (unsigned j = t; j < n; j += 1024) {
    unsigned p = gb + j;
    if (p < CAP_C) cand[(size_t)b * CAP_C + p] = s_w[j];
  }
}

// One block per batch: bitonic sort CAP_C keys descending, gather sorted boxes.
__global__ void __launch_bounds__(1024) sort_kernel(const u64* __restrict__ cand,
                                                    const unsigned* __restrict__ cntp,
                                                    const float4* __restrict__ boxes,
                                                    float4* __restrict__ sboxes,
                                                    float* __restrict__ sscore,
                                                    int N) {
  __shared__ u64 sk[CAP_C];  // 16 KB
  int b = blockIdx.x, t = threadIdx.x;
  int cnt = (int)cntp[b * CNT_STRIDE];
  if (cnt > CAP_C) cnt = CAP_C;
  for (int i = t; i < CAP_C; i += 1024)
    sk[i] = (i < cnt) ? cand[(size_t)b * CAP_C + i] : 0ull;  // pad sinks to end
  __syncthreads();
  for (unsigned kk = 2; kk <= CAP_C; kk <<= 1) {
    for (unsigned j = kk >> 1; j >= 1u; j >>= 1) {
      unsigned pid = (unsigned)t;  // exactly CAP_C/2 pairs
      unsigned i = ((pid & ~(j - 1u)) << 1) | (pid & (j - 1u));
      unsigned p = i | j;
      u64 va = sk[i], vb = sk[p];
      bool up = ((i & kk) == 0u);
      bool sw = up ? (va < vb) : (va > vb);
      if (sw) { sk[i] = vb; sk[p] = va; }
      __syncthreads();
    }
  }
  for (int i = t; i < CAP_C; i += 1024) {
    u64 key = sk[i];
    float4 bx = make_float4(0.f, 0.f, 0.f, 0.f);
    float sc = -__builtin_inff();
    if (i < cnt) {
      unsigned idx = ~(unsigned)(key & 0xFFFFFFFFull);
      bx = boxes[(size_t)b * N + idx];
      unsigned u = (unsigned)(key >> 32);
      unsigned sb2 = (u & 0x80000000u) ? (u ^ 0x80000000u) : ~u;
      sc = __uint_as_float(sb2);
    }
    sboxes[(size_t)b * CAP_C + i] = bx;
    sscore[(size_t)b * CAP_C + i] = sc;
  }
}

// Pairwise suppression masks: bit l of word w in row i <=> IoU(i, 64w+l) > 0.7.
__global__ void __launch_bounds__(256) mask_kernel(const float4* __restrict__ sboxes,
                                                   u64* __restrict__ mask) {
#pragma clang fp contract(off)
  __shared__ float4 sb[CAP_C];  // 32 KB
  int b = blockIdx.y, t = threadIdx.x;
  int wave = t >> 6, lane = t & 63;
  const float4* src = sboxes + (size_t)b * CAP_C;
  for (int i = t; i < CAP_C; i += 256) sb[i] = src[i];
  __syncthreads();
  for (int r = 0; r < MROWS; ++r) {
    int row = blockIdx.x * MROWS + r;
    float4 rb = sb[row];                       // broadcast read
    float ra = (rb.z - rb.x) * (rb.w - rb.y);  // picked-box area (barea)
    for (int chunk = wave; chunk < NW; chunk += 4) {
      float4 cb = sb[chunk * 64 + lane];
      float ix1 = fmaxf(rb.x, cb.x), iy1 = fmaxf(rb.y, cb.y);
      float ix2 = fminf(rb.z, cb.z), iy2 = fminf(rb.w, cb.w);
      float inter = fmaxf(ix2 - ix1, 0.0f) * fmaxf(iy2 - iy1, 0.0f);
      float ca = (cb.z - cb.x) * (cb.w - cb.y);
      float iou = inter / (ra + ca - inter + 1e-9f);
      u64 bal = __ballot(iou > 0.7f);
      if (lane == 0)
        mask[((size_t)b * CAP_C + row) * NW + chunk] = bal;
    }
  }
}

// ---- Walk v7: producer/consumer LDS pipeline, no inline asm.
// Round-9 lesson: asm-issued loads into compiler registers crash (async HW
// writes vs compiler's "defined at asm" model). Stage through LDS instead:
//   waves 1-3: load tile t+1 (16 KB, coalesced) into the spare LDS buffer —
//              their load-latency stall overlaps wave 0's work, ends at the
//              single per-tile __syncthreads (which drains vmcnt/lgkmcnt).
//   wave 0:    resolve tile t (v5's O(#suppressions) ballot resolve,
//              bit-identical keeps) + apply (64 independent ds_read_b64,
//              keep-masked OR-tree) into register-held `removed`.
// LDS rows padded to WP=33 words so the D-column read is bank-conflict-free.
// ONE barrier per tile; stop flag double-buffered in s_ctl.

__global__ void __launch_bounds__(256, 1) walk_kernel(const u64* __restrict__ mask,
                                                      const float4* __restrict__ sboxes,
                                                      const float* __restrict__ sscore,
                                                      const unsigned* __restrict__ cntp,
                                                      float* __restrict__ out, int K) {
  __shared__ u64 s_buf[2][64 * WP];   // 2 x 16.5 KB staged tiles
  __shared__ int s_keep[KMAX];
  __shared__ int s_ctl[4];            // [tt&1]: stop flag, [2]: nk
  const int b = blockIdx.x;
  const int t = threadIdx.x;
  const int wave = t >> 6, lane = t & 63;
  const u64* M = mask + (size_t)b * CAP_C * NW;
  int cnt = (int)cntp[b * CNT_STRIDE];
  if (cnt > CAP_C) cnt = CAP_C;
  const u64 lane_above = (lane == 63) ? 0ull : (~0ull << (lane + 1));

  // prologue: all 256 threads stage tile 0 (2048 u64, coalesced)
  for (int k = 0; k < 8; ++k) {
    int e = k * 256 + t;
    s_buf[0][(e >> 5) * WP + (e & 31)] = M[e];
  }
  if (t == 0) { s_ctl[0] = 0; s_ctl[1] = 0; s_ctl[2] = 0; }
  __syncthreads();

  u64 removed = 0ull;   // wave0: lanes 0..31 hold suppression words 0..31
  int nk = 0;           // wave0-maintained keep count
  int base = 0;
  int cur = 0;

  for (int tt = 0; tt < CAP_C / 64; ++tt) {
    int par = tt & 1;
    if (wave != 0) {
      // ---- producer: stage tile tt+1 into the spare buffer
      int nt = base + 64;
      if (nt > CAP_C - 64) nt = CAP_C - 64;   // clamp: full tile stays in-bounds
      const u64* src = M + (size_t)nt * NW;
      u64* dst = s_buf[cur ^ 1];
      int s = t - 64;                          // 0..191
      for (int k = 0; k < 11; ++k) {
        int e = k * 192 + s;
        if (e < 64 * NW)
          dst[(e >> 5) * WP + (e & 31)] = src[e];
      }
    } else {
      // ---- consumer (wave 0): resolve tile tt from staged buffer
      const u64* buf = s_buf[cur];
      int tw = base >> 6;                      // 0..31
      u64 D = buf[(size_t)lane * WP + tw];     // lane j = row j's tile-diag word
      unsigned rlo = __builtin_amdgcn_readlane((unsigned)(removed & 0xFFFFFFFFull), tw);
      unsigned rhi = __builtin_amdgcn_readlane((unsigned)(removed >> 32), tw);
      u64 in_rm = ((u64)rhi << 32) | (u64)rlo;
      int rem = cnt - base;
      u64 valid = (rem >= 64) ? ~0ull : ((rem <= 0) ? 0ull : ((1ull << rem) - 1ull));
      u64 pend = (~in_rm) & valid;
      u64 keep = 0ull;
      while (pend != 0ull) {                   // O(#suppressing keeps) trips
        bool cond = ((pend >> lane) & 1ull) && ((D & pend & lane_above) != 0ull);
        u64 bal = __ballot((int)cond);
        if (bal == 0ull) { keep |= pend; break; }
        int f = __builtin_ctzll(bal);
        u64 beq = (2ull << f) - 1ull;          // bits <= f (f=63 wraps to ~0)
        keep |= pend & beq;
        unsigned dlo = __builtin_amdgcn_readlane((unsigned)(D & 0xFFFFFFFFull), f);
        unsigned dhi = __builtin_amdgcn_readlane((unsigned)(D >> 32), f);
        u64 rowf = ((u64)dhi << 32) | (u64)dlo;
        pend &= ~beq;
        pend &= ~rowf;
      }
      int cap = K - nk;
      int kc = __popcll(keep);
      if (kc > cap) {                          // exact greedy K-cutoff
        bool mine = ((keep >> lane) & 1ull) &&
                    (__popcll(keep & ((1ull << lane) - 1ull)) < cap);
        keep = __ballot((int)mine);
        kc = cap;
      }
      if ((keep >> lane) & 1ull)
        s_keep[nk + __popcll(keep & ((1ull << lane) - 1ull))] = base + lane;
      nk += kc;
      // ---- apply: 64 independent LDS row-reads, keep-masked OR-tree
      int lw = lane & 31;
      u64 ac0 = 0, ac1 = 0, ac2 = 0, ac3 = 0;
#pragma unroll
      for (int r = 0; r < 64; r += 4) {
        u64 m0 = buf[(size_t)(r + 0) * WP + lw];
        u64 m1 = buf[(size_t)(r + 1) * WP + lw];
        u64 m2 = buf[(size_t)(r + 2) * WP + lw];
        u64 m3 = buf[(size_t)(r + 3) * WP + lw];
        ac0 |= m0 & ((u64)0 - ((keep >> (r + 0)) & 1ull));
        ac1 |= m1 & ((u64)0 - ((keep >> (r + 1)) & 1ull));
        ac2 |= m2 & ((u64)0 - ((keep >> (r + 2)) & 1ull));
        ac3 |= m3 & ((u64)0 - ((keep >> (r + 3)) & 1ull));
      }
      removed |= (ac0 | ac1) | (ac2 | ac3);
      int stop = (base + 64 >= cnt) || (nk >= K);
      if (lane == 0) { s_ctl[par] = stop; s_ctl[2] = nk; }
    }
    __syncthreads();                           // staging done + stop/nk visible
    if (s_ctl[par]) break;                     // uniform exit
    base += 64;
    cur ^= 1;
  }
  __syncthreads();
  int nkf = s_ctl[2];
  for (int j = t; j < nkf; j += 256) {
    int i = s_keep[j];
    float4 bx = sboxes[(size_t)b * CAP_C + i];
    float sc = sscore[(size_t)b * CAP_C + i];
    float* row = out + ((size_t)b * K + j) * 6;
    row[0] = bx.x; row[1] = bx.y; row[2] = bx.z; row[3] = bx.w;
    row[4] = sc; row[5] = 1.0f;
  }
  for (int j = nkf + t; j < K; j += 256) {     // zero invalid tail rows
    float* row = out + ((size_t)b * K + j) * 6;
    row[0] = 0.f; row[1] = 0.f; row[2] = 0.f; row[3] = 0.f;
    row[4] = 0.f; row[5] = 0.f;
  }
}

extern "C" void kernel_launch(void* const* d_in, const int* in_sizes, int n_in,
                              void* d_out, int out_size, void* d_ws, size_t ws_size,
                              hipStream_t stream) {
  const float4* anchors = (const float4*)d_in[0];
  const float4* deltas = (const float4*)d_in[1];
  const float* obj = (const float*)d_in[2];
  const int* imh = (const int*)d_in[3];
  const int* imw = (const int*)d_in[4];
  int N = in_sizes[0] / 4;
  int B = in_sizes[2] / N;
  int K = out_size / (B * 6);
  if (K > KMAX) K = KMAX;

  // ws layout (alignment-descending)
  char* ws = (char*)d_ws;
  size_t off = 0;
  float4* boxes = (float4*)(ws + off);            off += (size_t)B * N * 16;
  float4* sboxes = (float4*)(ws + off);           off += (size_t)B * CAP_C * 16;
  u64* cand = (u64*)(ws + off);                   off += (size_t)B * CAP_C * 8;
  u64* mask = (u64*)(ws + off);                   off += (size_t)B * CAP_C * NW * 8;
  unsigned* keys = (unsigned*)(ws + off);         off += (size_t)B * N * 4;
  unsigned* hist = (unsigned*)(ws + off);         off += (size_t)B * NBINS * 4;
  float* sscore = (float*)(ws + off);             off += (size_t)B * CAP_C * 4;
  unsigned* T_lo = (unsigned*)(ws + off);         off += (size_t)B * 4;
  off = (off + 255) & ~(size_t)255;               // cnt on its own lines
  unsigned* cnt = (unsigned*)(ws + off);          off += (size_t)B * CNT_STRIDE * 4;
  float* out = (float*)d_out;

  int nb = (N + 255) / 256;
  int P = (N + HE - 1) / HE;
  decode_kernel<<<nb, 256, 0, stream>>>(anchors, deltas, obj, imh, imw,
                                        boxes, keys, hist, N, B);
  hist_kernel<<<dim3(P, 2, B), HB, 0, stream>>>(keys, hist, N);
  threshold_kernel<<<B, 256, 0, stream>>>(hist, T_lo, cnt);
  compact_kernel<<<dim3(CPB, B), 1024, 0, stream>>>(keys, T_lo, cand, cnt, N);
  sort_kernel<<<B, 1024, 0, stream>>>(cand, cnt, boxes, sboxes, sscore, N);
  mask_kernel<<<dim3(CAP_C / MROWS, B), 256, 0, stream>>>(sboxes, mask);
  walk_kernel<<<B, 256, 0, stream>>>(mask, sboxes, sscore, cnt, out, K);
}

// Round 11
// 208.582 us; speedup vs baseline: 1.0388x; 1.0388x over previous
//
#include <hip/hip_runtime.h>
#include <cstdint>
#include <cstddef>

#define NBINS 32768         // 15-bit histogram of orderable score (u >> 17)
#define FINB 64u            // bin >= 64 <=> finite score (15-bit space)
#define CAP_C 2048          // candidate pool (pow2, = sort size)
#define NW (CAP_C / 64)     // 64-bit mask words per row = 32
#define WP (NW + 1)         // padded LDS row stride (kills D-column bank conflict)
#define TARGET 1792u        // threshold target (headroom to CAP_C)
#define KMAX 1008           // kept-list capacity
#define MROWS 16            // rows per mask block
#define HB 1024             // hist block threads
#define HE 32768            // keys per hist block (16-bit pack: counts <= HE < 65536)
#define CNT_STRIDE 64       // cnt[b*64]: 256B per counter, no shared lines

typedef unsigned long long u64;

__device__ __forceinline__ unsigned orderable(float f) {
  unsigned b = __float_as_uint(f);
  return (b & 0x80000000u) ? ~b : (b | 0x80000000u);
}

// Pure streaming: also zero-fills hist (no separate init dispatch).
__global__ void decode_kernel(const float4* __restrict__ anchors,
                              const float4* __restrict__ deltas,
                              const float* __restrict__ obj,
                              const int* __restrict__ im_h_p,
                              const int* __restrict__ im_w_p,
                              float4* __restrict__ boxes,
                              unsigned* __restrict__ keys,
                              unsigned* __restrict__ hist,
                              int N, int B) {
#pragma clang fp contract(off)
  int n = blockIdx.x * blockDim.x + threadIdx.x;
  int stride = gridDim.x * blockDim.x;
  for (int j = n; j < B * NBINS; j += stride) hist[j] = 0u;
  if (n >= N) return;
  float imw = (float)(*im_w_p);
  float imh = (float)(*im_h_p);
  float4 a = anchors[n];
  float aw = a.z - a.x;
  float ah = a.w - a.y;
  float acx = a.x + 0.5f * aw;
  float acy = a.y + 0.5f * ah;
  const float LOGM = 4.135166556742356f;  // log(1000/16) rounded to f32
  for (int b = 0; b < B; ++b) {
    size_t off = (size_t)b * N + n;
    float4 d = deltas[off];
    float dw = fminf(d.z, LOGM), dh = fminf(d.w, LOGM);
    float pcx = d.x * aw + acx;
    float pcy = d.y * ah + acy;
    float pw = expf(dw) * aw;
    float ph = expf(dh) * ah;
    float x1 = fminf(fmaxf(pcx - 0.5f * pw, 0.0f), imw);
    float y1 = fminf(fmaxf(pcy - 0.5f * ph, 0.0f), imh);
    float x2 = fminf(fmaxf(pcx + 0.5f * pw, 0.0f), imw);
    float y2 = fminf(fmaxf(pcy + 0.5f * ph, 0.0f), imh);
    boxes[off] = make_float4(x1, y1, x2, y2);
    float area = (x2 - x1) * (y2 - y1);
    float sc = (area > 1.0f) ? obj[off] : -__builtin_inff();
    keys[off] = orderable(sc);
  }
}

// LDS-privatized histogram, single pass (15-bit bins fit 64 KB LDS exactly:
// 32768 bins x 16-bit packed pairs). Grid (N/HE, B). Vectorized key loads.
__global__ void __launch_bounds__(HB) hist_kernel(const unsigned* __restrict__ keys,
                                                  unsigned* __restrict__ hist,
                                                  int N) {
  __shared__ unsigned hl[NBINS / 2];  // 16384 uints = 64 KB
  int t = threadIdx.x, b = blockIdx.y;
  for (int i = t; i < NBINS / 2; i += HB) hl[i] = 0u;
  __syncthreads();
  const uint4* kb = (const uint4*)(keys + (size_t)b * N) + (size_t)blockIdx.x * (HE / 4);
  int lim = HE / 4;
  int rem4 = (N - blockIdx.x * HE) / 4;
  if (lim > rem4) lim = rem4;
  for (int i = t; i < lim; i += HB) {
    uint4 v = kb[i];
    unsigned b0 = v.x >> 17, b1 = v.y >> 17, b2 = v.z >> 17, b3 = v.w >> 17;
    atomicAdd(&hl[b0 >> 1], (b0 & 1u) ? 65536u : 1u);
    atomicAdd(&hl[b1 >> 1], (b1 & 1u) ? 65536u : 1u);
    atomicAdd(&hl[b2 >> 1], (b2 & 1u) ? 65536u : 1u);
    atomicAdd(&hl[b3 >> 1], (b3 & 1u) ? 65536u : 1u);
  }
  __syncthreads();
  unsigned* hg = hist + (size_t)b * NBINS;
  for (int i = t; i < NBINS / 2; i += HB) {
    unsigned v = hl[i];
    unsigned clo = v & 0xFFFFu, chi = v >> 16;
    if (clo) atomicAdd(&hg[2 * i], clo);
    if (chi) atomicAdd(&hg[2 * i + 1], chi);
  }
}

// One 1024-thread block per batch: pick bin threshold so [T_lo, NBINS) holds
// ~TARGET candidates (<= CAP_C, boundary-bin exclusion preserves exactness).
__global__ void __launch_bounds__(1024) threshold_kernel(const unsigned* __restrict__ hist,
                                                         unsigned* __restrict__ T_lo) {
  const int BPT = NBINS / 1024;  // 32 bins/thread, contiguous ownership
  __shared__ unsigned s_part[1024];
  __shared__ unsigned s_T;
  int b = blockIdx.x, t = threadIdx.x;
  const unsigned* h = hist + (size_t)b * NBINS;
  if (t == 0) s_T = 0xFFFFFFFFu;
  unsigned mysum = 0;
  const uint4* h4 = (const uint4*)(h + t * BPT);
  for (int k = 0; k < BPT / 4; ++k) {  // 8 uint4s
    int bin0 = t * BPT + k * 4;
    if (bin0 >= (int)FINB) {  // FINB % 4 == 0
      uint4 v = h4[k];
      mysum += v.x + v.y + v.z + v.w;
    }
  }
  s_part[t] = mysum;
  __syncthreads();
  for (int d = 1; d < 1024; d <<= 1) {  // inclusive suffix sum
    unsigned v = (t + d < 1024) ? s_part[t + d] : 0u;
    __syncthreads();
    s_part[t] += v;
    __syncthreads();
  }
  unsigned total = s_part[0];
  unsigned target = (TARGET < total) ? TARGET : total;
  unsigned above = (t + 1 < 1024) ? s_part[t + 1] : 0u;
  if (total > 0u && above < target && s_part[t] >= target) {  // unique crossing thread
    unsigned c = above;
    for (int k = BPT - 1; k >= 0; --k) {
      unsigned bin = (unsigned)(t * BPT + k);
      if (bin < FINB) break;
      unsigned hv = h[bin];
      c += hv;
      if (c >= target) {
        unsigned T = bin;
        if (c > CAP_C && (c - hv) > 0u) T = bin + 1u;  // never overflow CAP_C
        s_T = T;
        break;
      }
    }
  }
  __syncthreads();
  if (t == 0) T_lo[b] = (total == 0u) ? 0xFFFFFFFFu : s_T;
}

// sort v2 (fused compact): one block per batch filters keys above threshold
// straight into LDS, bitonic-sorts descending, writes sorted boxes/scores/cnt.
// Bitonic barriers only for j >= 64: for j <= 32 (and transitions from j=64),
// every element's producer/consumer pids lie in the same wave (owner wave of
// element e is e>>7 for all phases with j <= 64), so wave-lockstep + in-order
// DS make __syncthreads unnecessary. 67 -> ~17 barriers.
__global__ void __launch_bounds__(1024) sort_kernel(const unsigned* __restrict__ keys,
                                                    const unsigned* __restrict__ T_lo,
                                                    const float4* __restrict__ boxes,
                                                    float4* __restrict__ sboxes,
                                                    float* __restrict__ sscore,
                                                    unsigned* __restrict__ cntw,
                                                    int N) {
  __shared__ u64 sk[CAP_C];  // 16 KB
  __shared__ unsigned s_n;
  int b = blockIdx.x, t = threadIdx.x;
  if (t == 0) s_n = 0u;
  for (int i = t; i < CAP_C; i += 1024) sk[i] = 0ull;  // pad sinks to end
  __syncthreads();
  unsigned T = T_lo[b];
  const uint4* k4 = (const uint4*)(keys + (size_t)b * N);
  for (int i = t; i < N / 4; i += 1024) {
    uint4 v = k4[i];
    int bi = i * 4;
    if ((v.x >> 17) >= T) { unsigned p = atomicAdd(&s_n, 1u); if (p < CAP_C) sk[p] = ((u64)v.x << 32) | (unsigned)(~(bi + 0)); }
    if ((v.y >> 17) >= T) { unsigned p = atomicAdd(&s_n, 1u); if (p < CAP_C) sk[p] = ((u64)v.y << 32) | (unsigned)(~(bi + 1)); }
    if ((v.z >> 17) >= T) { unsigned p = atomicAdd(&s_n, 1u); if (p < CAP_C) sk[p] = ((u64)v.z << 32) | (unsigned)(~(bi + 2)); }
    if ((v.w >> 17) >= T) { unsigned p = atomicAdd(&s_n, 1u); if (p < CAP_C) sk[p] = ((u64)v.w << 32) | (unsigned)(~(bi + 3)); }
  }
  __syncthreads();
  int cnt = (int)s_n;
  if (cnt > CAP_C) cnt = CAP_C;
  if (t == 0) cntw[b * CNT_STRIDE] = (unsigned)cnt;
  // descending bitonic sort; ~i low bits give argmax lowest-index tie-break
  for (unsigned kk = 2; kk <= CAP_C; kk <<= 1) {
    for (unsigned j = kk >> 1; j >= 1u; j >>= 1) {
      if (j >= 64u) __syncthreads();  // inter-wave phases only
      unsigned pid = (unsigned)t;     // exactly CAP_C/2 pairs
      unsigned i = ((pid & ~(j - 1u)) << 1) | (pid & (j - 1u));
      unsigned p = i | j;
      u64 va = sk[i], vb = sk[p];
      bool up = ((i & kk) == 0u);
      bool sw = up ? (va < vb) : (va > vb);
      if (sw) { sk[i] = vb; sk[p] = va; }
    }
  }
  __syncthreads();
  for (int i = t; i < CAP_C; i += 1024) {
    u64 key = sk[i];
    float4 bx = make_float4(0.f, 0.f, 0.f, 0.f);
    float sc = -__builtin_inff();
    if (i < cnt) {
      unsigned idx = ~(unsigned)(key & 0xFFFFFFFFull);
      bx = boxes[(size_t)b * N + idx];
      unsigned u = (unsigned)(key >> 32);
      unsigned sb2 = (u & 0x80000000u) ? (u ^ 0x80000000u) : ~u;
      sc = __uint_as_float(sb2);
    }
    sboxes[(size_t)b * CAP_C + i] = bx;
    sscore[(size_t)b * CAP_C + i] = sc;
  }
}

// Pairwise suppression masks: bit l of word w in row i <=> IoU(i, 64w+l) > 0.7.
__global__ void __launch_bounds__(256) mask_kernel(const float4* __restrict__ sboxes,
                                                   u64* __restrict__ mask) {
#pragma clang fp contract(off)
  __shared__ float4 sb[CAP_C];  // 32 KB
  int b = blockIdx.y, t = threadIdx.x;
  int wave = t >> 6, lane = t & 63;
  const float4* src = sboxes + (size_t)b * CAP_C;
  for (int i = t; i < CAP_C; i += 256) sb[i] = src[i];
  __syncthreads();
  for (int r = 0; r < MROWS; ++r) {
    int row = blockIdx.x * MROWS + r;
    float4 rb = sb[row];                       // broadcast read
    float ra = (rb.z - rb.x) * (rb.w - rb.y);  // picked-box area (barea)
    for (int chunk = wave; chunk < NW; chunk += 4) {
      float4 cb = sb[chunk * 64 + lane];
      float ix1 = fmaxf(rb.x, cb.x), iy1 = fmaxf(rb.y, cb.y);
      float ix2 = fminf(rb.z, cb.z), iy2 = fminf(rb.w, cb.w);
      float inter = fmaxf(ix2 - ix1, 0.0f) * fmaxf(iy2 - iy1, 0.0f);
      float ca = (cb.z - cb.x) * (cb.w - cb.y);
      float iou = inter / (ra + ca - inter + 1e-9f);
      u64 bal = __ballot(iou > 0.7f);
      if (lane == 0)
        mask[((size_t)b * CAP_C + row) * NW + chunk] = bal;
    }
  }
}

// ---- Walk v7 (round-10): producer/consumer LDS pipeline, no inline asm.
// waves 1-3 stage tile t+1 into spare LDS buffer (latency overlaps wave 0);
// wave 0 resolves tile t with the O(#suppressions) ballot resolve + LDS apply.
// One __syncthreads per tile; stop flag double-buffered.
__global__ void __launch_bounds__(256, 1) walk_kernel(const u64* __restrict__ mask,
                                                      const float4* __restrict__ sboxes,
                                                      const float* __restrict__ sscore,
                                                      const unsigned* __restrict__ cntp,
                                                      float* __restrict__ out, int K) {
  __shared__ u64 s_buf[2][64 * WP];   // 2 x 16.5 KB staged tiles
  __shared__ int s_keep[KMAX];
  __shared__ int s_ctl[4];            // [tt&1]: stop flag, [2]: nk
  const int b = blockIdx.x;
  const int t = threadIdx.x;
  const int wave = t >> 6, lane = t & 63;
  const u64* M = mask + (size_t)b * CAP_C * NW;
  int cnt = (int)cntp[b * CNT_STRIDE];
  if (cnt > CAP_C) cnt = CAP_C;
  const u64 lane_above = (lane == 63) ? 0ull : (~0ull << (lane + 1));

  // prologue: all 256 threads stage tile 0 (2048 u64, coalesced)
  for (int k = 0; k < 8; ++k) {
    int e = k * 256 + t;
    s_buf[0][(e >> 5) * WP + (e & 31)] = M[e];
  }
  if (t == 0) { s_ctl[0] = 0; s_ctl[1] = 0; s_ctl[2] = 0; }
  __syncthreads();

  u64 removed = 0ull;   // wave0: lanes 0..31 hold suppression words 0..31
  int nk = 0;           // wave0-maintained keep count
  int base = 0;
  int cur = 0;

  for (int tt = 0; tt < CAP_C / 64; ++tt) {
    int par = tt & 1;
    if (wave != 0) {
      // ---- producer: stage tile tt+1 into the spare buffer
      int nt = base + 64;
      if (nt > CAP_C - 64) nt = CAP_C - 64;   // clamp: full tile stays in-bounds
      const u64* src = M + (size_t)nt * NW;
      u64* dst = s_buf[cur ^ 1];
      int s = t - 64;                          // 0..191
      for (int k = 0; k < 11; ++k) {
        int e = k * 192 + s;
        if (e < 64 * NW)
          dst[(e >> 5) * WP + (e & 31)] = src[e];
      }
    } else {
      // ---- consumer (wave 0): resolve tile tt from staged buffer
      const u64* buf = s_buf[cur];
      int tw = base >> 6;                      // 0..31
      u64 D = buf[(size_t)lane * WP + tw];     // lane j = row j's tile-diag word
      unsigned rlo = __builtin_amdgcn_readlane((unsigned)(removed & 0xFFFFFFFFull), tw);
      unsigned rhi = __builtin_amdgcn_readlane((unsigned)(removed >> 32), tw);
      u64 in_rm = ((u64)rhi << 32) | (u64)rlo;
      int rem = cnt - base;
      u64 valid = (rem >= 64) ? ~0ull : ((rem <= 0) ? 0ull : ((1ull << rem) - 1ull));
      u64 pend = (~in_rm) & valid;
      u64 keep = 0ull;
      while (pend != 0ull) {                   // O(#suppressing keeps) trips
        bool cond = ((pend >> lane) & 1ull) && ((D & pend & lane_above) != 0ull);
        u64 bal = __ballot((int)cond);
        if (bal == 0ull) { keep |= pend; break; }
        int f = __builtin_ctzll(bal);
        u64 beq = (2ull << f) - 1ull;          // bits <= f (f=63 wraps to ~0)
        keep |= pend & beq;
        unsigned dlo = __builtin_amdgcn_readlane((unsigned)(D & 0xFFFFFFFFull), f);
        unsigned dhi = __builtin_amdgcn_readlane((unsigned)(D >> 32), f);
        u64 rowf = ((u64)dhi << 32) | (u64)dlo;
        pend &= ~beq;
        pend &= ~rowf;
      }
      int cap = K - nk;
      int kc = __popcll(keep);
      if (kc > cap) {                          // exact greedy K-cutoff
        bool mine = ((keep >> lane) & 1ull) &&
                    (__popcll(keep & ((1ull << lane) - 1ull)) < cap);
        keep = __ballot((int)mine);
        kc = cap;
      }
      if ((keep >> lane) & 1ull)
        s_keep[nk + __popcll(keep & ((1ull << lane) - 1ull))] = base + lane;
      nk += kc;
      // ---- apply: 64 independent LDS row-reads, keep-masked OR-tree
      int lw = lane & 31;
      u64 ac0 = 0, ac1 = 0, ac2 = 0, ac3 = 0;
#pragma unroll
      for (int r = 0; r < 64; r += 4) {
        u64 m0 = buf[(size_t)(r + 0) * WP + lw];
        u64 m1 = buf[(size_t)(r + 1) * WP + lw];
        u64 m2 = buf[(size_t)(r + 2) * WP + lw];
        u64 m3 = buf[(size_t)(r + 3) * WP + lw];
        ac0 |= m0 & ((u64)0 - ((keep >> (r + 0)) & 1ull));
        ac1 |= m1 & ((u64)0 - ((keep >> (r + 1)) & 1ull));
        ac2 |= m2 & ((u64)0 - ((keep >> (r + 2)) & 1ull));
        ac3 |= m3 & ((u64)0 - ((keep >> (r + 3)) & 1ull));
      }
      removed |= (ac0 | ac1) | (ac2 | ac3);
      int stop = (base + 64 >= cnt) || (nk >= K);
      if (lane == 0) { s_ctl[par] = stop; s_ctl[2] = nk; }
    }
    __syncthreads();                           // staging done + stop/nk visible
    if (s_ctl[par]) break;                     // uniform exit
    base += 64;
    cur ^= 1;
  }
  __syncthreads();
  int nkf = s_ctl[2];
  for (int j = t; j < nkf; j += 256) {
    int i = s_keep[j];
    float4 bx = sboxes[(size_t)b * CAP_C + i];
    float sc = sscore[(size_t)b * CAP_C + i];
    float* row = out + ((size_t)b * K + j) * 6;
    row[0] = bx.x; row[1] = bx.y; row[2] = bx.z; row[3] = bx.w;
    row[4] = sc; row[5] = 1.0f;
  }
  for (int j = nkf + t; j < K; j += 256) {     // zero invalid tail rows
    float* row = out + ((size_t)b * K + j) * 6;
    row[0] = 0.f; row[1] = 0.f; row[2] = 0.f; row[3] = 0.f;
    row[4] = 0.f; row[5] = 0.f;
  }
}

extern "C" void kernel_launch(void* const* d_in, const int* in_sizes, int n_in,
                              void* d_out, int out_size, void* d_ws, size_t ws_size,
                              hipStream_t stream) {
  const float4* anchors = (const float4*)d_in[0];
  const float4* deltas = (const float4*)d_in[1];
  const float* obj = (const float*)d_in[2];
  const int* imh = (const int*)d_in[3];
  const int* imw = (const int*)d_in[4];
  int N = in_sizes[0] / 4;
  int B = in_sizes[2] / N;
  int K = out_size / (B * 6);
  if (K > KMAX) K = KMAX;

  // ws layout (alignment-descending)
  char* ws = (char*)d_ws;
  size_t off = 0;
  float4* boxes = (float4*)(ws + off);            off += (size_t)B * N * 16;
  float4* sboxes = (float4*)(ws + off);           off += (size_t)B * CAP_C * 16;
  u64* mask = (u64*)(ws + off);                   off += (size_t)B * CAP_C * NW * 8;
  unsigned* keys = (unsigned*)(ws + off);         off += (size_t)B * N * 4;
  unsigned* hist = (unsigned*)(ws + off);         off += (size_t)B * NBINS * 4;
  float* sscore = (float*)(ws + off);             off += (size_t)B * CAP_C * 4;
  unsigned* T_lo = (unsigned*)(ws + off);         off += (size_t)B * 4;
  off = (off + 255) & ~(size_t)255;               // cnt on its own lines
  unsigned* cnt = (unsigned*)(ws + off);          off += (size_t)B * CNT_STRIDE * 4;
  float* out = (float*)d_out;

  int nb = (N + 255) / 256;
  int P = (N + HE - 1) / HE;
  decode_kernel<<<nb, 256, 0, stream>>>(anchors, deltas, obj, imh, imw,
                                        boxes, keys, hist, N, B);
  hist_kernel<<<dim3(P, B), HB, 0, stream>>>(keys, hist, N);
  threshold_kernel<<<B, 1024, 0, stream>>>(hist, T_lo);
  sort_kernel<<<B, 1024, 0, stream>>>(keys, T_lo, boxes, sboxes, sscore, cnt, N);
  mask_kernel<<<dim3(CAP_C / MROWS, B), 256, 0, stream>>>(sboxes, mask);
  walk_kernel<<<B, 256, 0, stream>>>(mask, sboxes, sscore, cnt, out, K);
}

// Round 12
// 173.174 us; speedup vs baseline: 1.2512x; 1.2045x over previous
//
#include <hip/hip_runtime.h>
#include <cstdint>
#include <cstddef>

#define NBINS 32768         // 15-bit histogram of orderable score (u >> 17)
#define FINB 64u            // bin >= 64 <=> finite score (15-bit space)
#define CAP_C 2048          // candidate pool (pow2, = sort size)
#define NW (CAP_C / 64)     // 64-bit mask words per row = 32
#define WP (NW + 1)         // padded LDS row stride (kills D-column bank conflict)
#define TARGET 1792u        // threshold target (headroom to CAP_C)
#define KMAX 1008           // kept-list capacity
#define MROWS 16            // rows per mask block
#define HB 1024             // hist block threads
#define HE 32768            // keys per hist block (16-bit pack: counts <= HE < 65536)
#define CNT_STRIDE 64       // cnt[b*64]: 256B per counter, no shared lines
#define CPB 64              // compact blocks per batch

typedef unsigned long long u64;

__device__ __forceinline__ unsigned orderable(float f) {
  unsigned b = __float_as_uint(f);
  return (b & 0x80000000u) ? ~b : (b | 0x80000000u);
}

// Pure streaming: also zero-fills hist (no separate init dispatch).
__global__ void decode_kernel(const float4* __restrict__ anchors,
                              const float4* __restrict__ deltas,
                              const float* __restrict__ obj,
                              const int* __restrict__ im_h_p,
                              const int* __restrict__ im_w_p,
                              float4* __restrict__ boxes,
                              unsigned* __restrict__ keys,
                              unsigned* __restrict__ hist,
                              int N, int B) {
#pragma clang fp contract(off)
  int n = blockIdx.x * blockDim.x + threadIdx.x;
  int stride = gridDim.x * blockDim.x;
  for (int j = n; j < B * NBINS; j += stride) hist[j] = 0u;
  if (n >= N) return;
  float imw = (float)(*im_w_p);
  float imh = (float)(*im_h_p);
  float4 a = anchors[n];
  float aw = a.z - a.x;
  float ah = a.w - a.y;
  float acx = a.x + 0.5f * aw;
  float acy = a.y + 0.5f * ah;
  const float LOGM = 4.135166556742356f;  // log(1000/16) rounded to f32
  for (int b = 0; b < B; ++b) {
    size_t off = (size_t)b * N + n;
    float4 d = deltas[off];
    float dw = fminf(d.z, LOGM), dh = fminf(d.w, LOGM);
    float pcx = d.x * aw + acx;
    float pcy = d.y * ah + acy;
    float pw = expf(dw) * aw;
    float ph = expf(dh) * ah;
    float x1 = fminf(fmaxf(pcx - 0.5f * pw, 0.0f), imw);
    float y1 = fminf(fmaxf(pcy - 0.5f * ph, 0.0f), imh);
    float x2 = fminf(fmaxf(pcx + 0.5f * pw, 0.0f), imw);
    float y2 = fminf(fmaxf(pcy + 0.5f * ph, 0.0f), imh);
    boxes[off] = make_float4(x1, y1, x2, y2);
    float area = (x2 - x1) * (y2 - y1);
    float sc = (area > 1.0f) ? obj[off] : -__builtin_inff();
    keys[off] = orderable(sc);
  }
}

// LDS-privatized histogram, single pass (15-bit bins fit 64 KB LDS exactly).
__global__ void __launch_bounds__(HB) hist_kernel(const unsigned* __restrict__ keys,
                                                  unsigned* __restrict__ hist,
                                                  int N) {
  __shared__ unsigned hl[NBINS / 2];  // 16384 uints = 64 KB
  int t = threadIdx.x, b = blockIdx.y;
  for (int i = t; i < NBINS / 2; i += HB) hl[i] = 0u;
  __syncthreads();
  const uint4* kb = (const uint4*)(keys + (size_t)b * N) + (size_t)blockIdx.x * (HE / 4);
  int lim = HE / 4;
  int rem4 = (N - blockIdx.x * HE) / 4;
  if (lim > rem4) lim = rem4;
  for (int i = t; i < lim; i += HB) {
    uint4 v = kb[i];
    unsigned b0 = v.x >> 17, b1 = v.y >> 17, b2 = v.z >> 17, b3 = v.w >> 17;
    atomicAdd(&hl[b0 >> 1], (b0 & 1u) ? 65536u : 1u);
    atomicAdd(&hl[b1 >> 1], (b1 & 1u) ? 65536u : 1u);
    atomicAdd(&hl[b2 >> 1], (b2 & 1u) ? 65536u : 1u);
    atomicAdd(&hl[b3 >> 1], (b3 & 1u) ? 65536u : 1u);
  }
  __syncthreads();
  unsigned* hg = hist + (size_t)b * NBINS;
  for (int i = t; i < NBINS / 2; i += HB) {
    unsigned v = hl[i];
    unsigned clo = v & 0xFFFFu, chi = v >> 16;
    if (clo) atomicAdd(&hg[2 * i], clo);
    if (chi) atomicAdd(&hg[2 * i + 1], chi);
  }
}

// One 1024-thread block per batch: pick bin threshold so [T_lo, NBINS) holds
// ~TARGET candidates (<= CAP_C). Also zeroes cnt[b*CNT_STRIDE] for compact.
__global__ void __launch_bounds__(1024) threshold_kernel(const unsigned* __restrict__ hist,
                                                         unsigned* __restrict__ T_lo,
                                                         unsigned* __restrict__ cnt) {
  const int BPT = NBINS / 1024;  // 32 bins/thread, contiguous ownership
  __shared__ unsigned s_part[1024];
  __shared__ unsigned s_T;
  int b = blockIdx.x, t = threadIdx.x;
  const unsigned* h = hist + (size_t)b * NBINS;
  if (t == 0) { s_T = 0xFFFFFFFFu; cnt[b * CNT_STRIDE] = 0u; }
  unsigned mysum = 0;
  const uint4* h4 = (const uint4*)(h + t * BPT);
  for (int k = 0; k < BPT / 4; ++k) {  // 8 uint4s
    int bin0 = t * BPT + k * 4;
    if (bin0 >= (int)FINB) {  // FINB % 4 == 0
      uint4 v = h4[k];
      mysum += v.x + v.y + v.z + v.w;
    }
  }
  s_part[t] = mysum;
  __syncthreads();
  for (int d = 1; d < 1024; d <<= 1) {  // inclusive suffix sum
    unsigned v = (t + d < 1024) ? s_part[t + d] : 0u;
    __syncthreads();
    s_part[t] += v;
    __syncthreads();
  }
  unsigned total = s_part[0];
  unsigned target = (TARGET < total) ? TARGET : total;
  unsigned above = (t + 1 < 1024) ? s_part[t + 1] : 0u;
  if (total > 0u && above < target && s_part[t] >= target) {  // unique crossing thread
    unsigned c = above;
    for (int k = BPT - 1; k >= 0; --k) {
      unsigned bin = (unsigned)(t * BPT + k);
      if (bin < FINB) break;
      unsigned hv = h[bin];
      c += hv;
      if (c >= target) {
        unsigned T = bin;
        if (c > CAP_C && (c - hv) > 0u) T = bin + 1u;  // never overflow CAP_C
        s_T = T;
        break;
      }
    }
  }
  __syncthreads();
  if (t == 0) T_lo[b] = (total == 0u) ? 0xFFFFFFFFu : s_T;
}

// compact (full-GPU grid, block-aggregated): round-11 fused this into sort's 4
// blocks -> 51.8us of per-CU-BW-limited scanning. Unfused again: 256 blocks
// scan 4 KB of keys each (one uint4/thread), LDS-stage winners, ONE
// reservation atomic per block, coalesced writes. Order within cand[] is
// irrelevant (sort imposes the total order on (score,~i)).
__global__ void __launch_bounds__(1024) compact_kernel(const unsigned* __restrict__ keys,
                                                       const unsigned* __restrict__ T_lo,
                                                       u64* __restrict__ cand,
                                                       unsigned* __restrict__ cnt, int N) {
  __shared__ u64 s_w[4096];  // 32 KB winner staging (total/batch <= ~2048)
  __shared__ unsigned s_n, s_base;
  int b = blockIdx.y, t = threadIdx.x;
  if (t == 0) s_n = 0u;
  __syncthreads();
  unsigned T = T_lo[b];
  int slice4 = N / 4 / CPB;  // uint4s per block (N=262144: 1024 -> 1/thread)
  const uint4* k4 = (const uint4*)(keys + (size_t)b * N) + (size_t)blockIdx.x * slice4;
  for (int i = t; i < slice4; i += 1024) {
    uint4 v = k4[i];
    int bi = (blockIdx.x * slice4 + i) * 4;
    if ((v.x >> 17) >= T) { unsigned p = atomicAdd(&s_n, 1u); if (p < 4096u) s_w[p] = ((u64)v.x << 32) | (unsigned)(~(bi + 0)); }
    if ((v.y >> 17) >= T) { unsigned p = atomicAdd(&s_n, 1u); if (p < 4096u) s_w[p] = ((u64)v.y << 32) | (unsigned)(~(bi + 1)); }
    if ((v.z >> 17) >= T) { unsigned p = atomicAdd(&s_n, 1u); if (p < 4096u) s_w[p] = ((u64)v.z << 32) | (unsigned)(~(bi + 2)); }
    if ((v.w >> 17) >= T) { unsigned p = atomicAdd(&s_n, 1u); if (p < 4096u) s_w[p] = ((u64)v.w << 32) | (unsigned)(~(bi + 3)); }
  }
  __syncthreads();
  unsigned n = s_n < 4096u ? s_n : 4096u;
  if (t == 0) s_base = (n > 0u) ? atomicAdd(&cnt[b * CNT_STRIDE], n) : 0u;
  __syncthreads();
  unsigned gb = s_base;
  for (unsigned j = t; j < n; j += 1024) {
    unsigned p = gb + j;
    if (p < CAP_C) cand[(size_t)b * CAP_C + p] = s_w[j];
  }
}

// One block per batch: bitonic sort CAP_C keys (16 KB from cand[]) descending,
// gather sorted boxes. Barriers only for j >= 64 phases (for j <= 32 every
// element's producer/consumer pids lie in one wave: owner wave of element e is
// e>>7 whenever j <= 64) -> 66 -> 15 barriers.
__global__ void __launch_bounds__(1024) sort_kernel(const u64* __restrict__ cand,
                                                    const unsigned* __restrict__ cntp,
                                                    const float4* __restrict__ boxes,
                                                    float4* __restrict__ sboxes,
                                                    float* __restrict__ sscore,
                                                    int N) {
  __shared__ u64 sk[CAP_C];  // 16 KB
  int b = blockIdx.x, t = threadIdx.x;
  int cnt = (int)cntp[b * CNT_STRIDE];
  if (cnt > CAP_C) cnt = CAP_C;
  for (int i = t; i < CAP_C; i += 1024)
    sk[i] = (i < cnt) ? cand[(size_t)b * CAP_C + i] : 0ull;  // pad sinks to end
  __syncthreads();
  for (unsigned kk = 2; kk <= CAP_C; kk <<= 1) {
    for (unsigned j = kk >> 1; j >= 1u; j >>= 1) {
      if (j >= 64u) __syncthreads();  // inter-wave phases only
      unsigned pid = (unsigned)t;     // exactly CAP_C/2 pairs
      unsigned i = ((pid & ~(j - 1u)) << 1) | (pid & (j - 1u));
      unsigned p = i | j;
      u64 va = sk[i], vb = sk[p];
      bool up = ((i & kk) == 0u);
      bool sw = up ? (va < vb) : (va > vb);
      if (sw) { sk[i] = vb; sk[p] = va; }
    }
  }
  __syncthreads();
  for (int i = t; i < CAP_C; i += 1024) {
    u64 key = sk[i];
    float4 bx = make_float4(0.f, 0.f, 0.f, 0.f);
    float sc = -__builtin_inff();
    if (i < cnt) {
      unsigned idx = ~(unsigned)(key & 0xFFFFFFFFull);
      bx = boxes[(size_t)b * N + idx];
      unsigned u = (unsigned)(key >> 32);
      unsigned sb2 = (u & 0x80000000u) ? (u ^ 0x80000000u) : ~u;
      sc = __uint_as_float(sb2);
    }
    sboxes[(size_t)b * CAP_C + i] = bx;
    sscore[(size_t)b * CAP_C + i] = sc;
  }
}

// Pairwise suppression masks: bit l of word w in row i <=> IoU(i, 64w+l) > 0.7.
__global__ void __launch_bounds__(256) mask_kernel(const float4* __restrict__ sboxes,
                                                   u64* __restrict__ mask) {
#pragma clang fp contract(off)
  __shared__ float4 sb[CAP_C];  // 32 KB
  int b = blockIdx.y, t = threadIdx.x;
  int wave = t >> 6, lane = t & 63;
  const float4* src = sboxes + (size_t)b * CAP_C;
  for (int i = t; i < CAP_C; i += 256) sb[i] = src[i];
  __syncthreads();
  for (int r = 0; r < MROWS; ++r) {
    int row = blockIdx.x * MROWS + r;
    float4 rb = sb[row];                       // broadcast read
    float ra = (rb.z - rb.x) * (rb.w - rb.y);  // picked-box area (barea)
    for (int chunk = wave; chunk < NW; chunk += 4) {
      float4 cb = sb[chunk * 64 + lane];
      float ix1 = fmaxf(rb.x, cb.x), iy1 = fmaxf(rb.y, cb.y);
      float ix2 = fminf(rb.z, cb.z), iy2 = fminf(rb.w, cb.w);
      float inter = fmaxf(ix2 - ix1, 0.0f) * fmaxf(iy2 - iy1, 0.0f);
      float ca = (cb.z - cb.x) * (cb.w - cb.y);
      float iou = inter / (ra + ca - inter + 1e-9f);
      u64 bal = __ballot(iou > 0.7f);
      if (lane == 0)
        mask[((size_t)b * CAP_C + row) * NW + chunk] = bal;
    }
  }
}

// ---- Walk v7: producer/consumer LDS pipeline (round-10).
// waves 1-3 stage tile t+1 into spare LDS buffer (latency overlaps wave 0);
// wave 0 resolves tile t with the O(#suppressions) ballot resolve + LDS apply.
// One __syncthreads per tile; stop flag double-buffered.
__global__ void __launch_bounds__(256, 1) walk_kernel(const u64* __restrict__ mask,
                                                      const float4* __restrict__ sboxes,
                                                      const float* __restrict__ sscore,
                                                      const unsigned* __restrict__ cntp,
                                                      float* __restrict__ out, int K) {
  __shared__ u64 s_buf[2][64 * WP];   // 2 x 16.5 KB staged tiles
  __shared__ int s_keep[KMAX];
  __shared__ int s_ctl[4];            // [tt&1]: stop flag, [2]: nk
  const int b = blockIdx.x;
  const int t = threadIdx.x;
  const int wave = t >> 6, lane = t & 63;
  const u64* M = mask + (size_t)b * CAP_C * NW;
  int cnt = (int)cntp[b * CNT_STRIDE];
  if (cnt > CAP_C) cnt = CAP_C;
  const u64 lane_above = (lane == 63) ? 0ull : (~0ull << (lane + 1));

  // prologue: all 256 threads stage tile 0 (2048 u64, coalesced)
  for (int k = 0; k < 8; ++k) {
    int e = k * 256 + t;
    s_buf[0][(e >> 5) * WP + (e & 31)] = M[e];
  }
  if (t == 0) { s_ctl[0] = 0; s_ctl[1] = 0; s_ctl[2] = 0; }
  __syncthreads();

  u64 removed = 0ull;   // wave0: lanes 0..31 hold suppression words 0..31
  int nk = 0;           // wave0-maintained keep count
  int base = 0;
  int cur = 0;

  for (int tt = 0; tt < CAP_C / 64; ++tt) {
    int par = tt & 1;
    if (wave != 0) {
      // ---- producer: stage tile tt+1 into the spare buffer
      int nt = base + 64;
      if (nt > CAP_C - 64) nt = CAP_C - 64;   // clamp: full tile stays in-bounds
      const u64* src = M + (size_t)nt * NW;
      u64* dst = s_buf[cur ^ 1];
      int s = t - 64;                          // 0..191
      for (int k = 0; k < 11; ++k) {
        int e = k * 192 + s;
        if (e < 64 * NW)
          dst[(e >> 5) * WP + (e & 31)] = src[e];
      }
    } else {
      // ---- consumer (wave 0): resolve tile tt from staged buffer
      const u64* buf = s_buf[cur];
      int tw = base >> 6;                      // 0..31
      u64 D = buf[(size_t)lane * WP + tw];     // lane j = row j's tile-diag word
      unsigned rlo = __builtin_amdgcn_readlane((unsigned)(removed & 0xFFFFFFFFull), tw);
      unsigned rhi = __builtin_amdgcn_readlane((unsigned)(removed >> 32), tw);
      u64 in_rm = ((u64)rhi << 32) | (u64)rlo;
      int rem = cnt - base;
      u64 valid = (rem >= 64) ? ~0ull : ((rem <= 0) ? 0ull : ((1ull << rem) - 1ull));
      u64 pend = (~in_rm) & valid;
      u64 keep = 0ull;
      while (pend != 0ull) {                   // O(#suppressing keeps) trips
        bool cond = ((pend >> lane) & 1ull) && ((D & pend & lane_above) != 0ull);
        u64 bal = __ballot((int)cond);
        if (bal == 0ull) { keep |= pend; break; }
        int f = __builtin_ctzll(bal);
        u64 beq = (2ull << f) - 1ull;          // bits <= f (f=63 wraps to ~0)
        keep |= pend & beq;
        unsigned dlo = __builtin_amdgcn_readlane((unsigned)(D & 0xFFFFFFFFull), f);
        unsigned dhi = __builtin_amdgcn_readlane((unsigned)(D >> 32), f);
        u64 rowf = ((u64)dhi << 32) | (u64)dlo;
        pend &= ~beq;
        pend &= ~rowf;
      }
      int cap = K - nk;
      int kc = __popcll(keep);
      if (kc > cap) {                          // exact greedy K-cutoff
        bool mine = ((keep >> lane) & 1ull) &&
                    (__popcll(keep & ((1ull << lane) - 1ull)) < cap);
        keep = __ballot((int)mine);
        kc = cap;
      }
      if ((keep >> lane) & 1ull)
        s_keep[nk + __popcll(keep & ((1ull << lane) - 1ull))] = base + lane;
      nk += kc;
      // ---- apply: 64 independent LDS row-reads, keep-masked OR-tree
      int lw = lane & 31;
      u64 ac0 = 0, ac1 = 0, ac2 = 0, ac3 = 0;
#pragma unroll
      for (int r = 0; r < 64; r += 4) {
        u64 m0 = buf[(size_t)(r + 0) * WP + lw];
        u64 m1 = buf[(size_t)(r + 1) * WP + lw];
        u64 m2 = buf[(size_t)(r + 2) * WP + lw];
        u64 m3 = buf[(size_t)(r + 3) * WP + lw];
        ac0 |= m0 & ((u64)0 - ((keep >> (r + 0)) & 1ull));
        ac1 |= m1 & ((u64)0 - ((keep >> (r + 1)) & 1ull));
        ac2 |= m2 & ((u64)0 - ((keep >> (r + 2)) & 1ull));
        ac3 |= m3 & ((u64)0 - ((keep >> (r + 3)) & 1ull));
      }
      removed |= (ac0 | ac1) | (ac2 | ac3);
      int stop = (base + 64 >= cnt) || (nk >= K);
      if (lane == 0) { s_ctl[par] = stop; s_ctl[2] = nk; }
    }
    __syncthreads();                           // staging done + stop/nk visible
    if (s_ctl[par]) break;                     // uniform exit
    base += 64;
    cur ^= 1;
  }
  __syncthreads();
  int nkf = s_ctl[2];
  for (int j = t; j < nkf; j += 256) {
    int i = s_keep[j];
    float4 bx = sboxes[(size_t)b * CAP_C + i];
    float sc = sscore[(size_t)b * CAP_C + i];
    float* row = out + ((size_t)b * K + j) * 6;
    row[0] = bx.x; row[1] = bx.y; row[2] = bx.z; row[3] = bx.w;
    row[4] = sc; row[5] = 1.0f;
  }
  for (int j = nkf + t; j < K; j += 256) {     // zero invalid tail rows
    float* row = out + ((size_t)b * K + j) * 6;
    row[0] = 0.f; row[1] = 0.f; row[2] = 0.f; row[3] = 0.f;
    row[4] = 0.f; row[5] = 0.f;
  }
}

extern "C" void kernel_launch(void* const* d_in, const int* in_sizes, int n_in,
                              void* d_out, int out_size, void* d_ws, size_t ws_size,
                              hipStream_t stream) {
  const float4* anchors = (const float4*)d_in[0];
  const float4* deltas = (const float4*)d_in[1];
  const float* obj = (const float*)d_in[2];
  const int* imh = (const int*)d_in[3];
  const int* imw = (const int*)d_in[4];
  int N = in_sizes[0] / 4;
  int B = in_sizes[2] / N;
  int K = out_size / (B * 6);
  if (K > KMAX) K = KMAX;

  // ws layout (alignment-descending)
  char* ws = (char*)d_ws;
  size_t off = 0;
  float4* boxes = (float4*)(ws + off);            off += (size_t)B * N * 16;
  float4* sboxes = (float4*)(ws + off);           off += (size_t)B * CAP_C * 16;
  u64* cand = (u64*)(ws + off);                   off += (size_t)B * CAP_C * 8;
  u64* mask = (u64*)(ws + off);                   off += (size_t)B * CAP_C * NW * 8;
  unsigned* keys = (unsigned*)(ws + off);         off += (size_t)B * N * 4;
  unsigned* hist = (unsigned*)(ws + off);         off += (size_t)B * NBINS * 4;
  float* sscore = (float*)(ws + off);             off += (size_t)B * CAP_C * 4;
  unsigned* T_lo = (unsigned*)(ws + off);         off += (size_t)B * 4;
  off = (off + 255) & ~(size_t)255;               // cnt on its own lines
  unsigned* cnt = (unsigned*)(ws + off);          off += (size_t)B * CNT_STRIDE * 4;
  float* out = (float*)d_out;

  int nb = (N + 255) / 256;
  int P = (N + HE - 1) / HE;
  decode_kernel<<<nb, 256, 0, stream>>>(anchors, deltas, obj, imh, imw,
                                        boxes, keys, hist, N, B);
  hist_kernel<<<dim3(P, B), HB, 0, stream>>>(keys, hist, N);
  threshold_kernel<<<B, 1024, 0, stream>>>(hist, T_lo, cnt);
  compact_kernel<<<dim3(CPB, B), 1024, 0, stream>>>(keys, T_lo, cand, cnt, N);
  sort_kernel<<<B, 1024, 0, stream>>>(cand, cnt, boxes, sboxes, sscore, N);
  mask_kernel<<<dim3(CAP_C / MROWS, B), 256, 0, stream>>>(sboxes, mask);
  walk_kernel<<<B, 256, 0, stream>>>(mask, sboxes, sscore, cnt, out, K);
}